// Round 6
// baseline (811.816 us; speedup 1.0000x reference)
//
#include <hip/hip_runtime.h>

// CRITICAL: HIP's __f*_rn are plain inline functions (a+b), NOT
// contraction-immune like CUDA's. hipcc default -ffp-contract=fast-honor-pragmas
// will fuse mul+add into v_fmac, breaking bit-exact replication of the numpy
// fp32 oracle. Disable contraction globally and per-function.
#pragma clang fp contract(off)

#define D4    83521      // 17^4 entries per LUT (per channel)
#define HW    262144     // 512*512
#define NPIX  2097152    // 8*512*512

// Pack one LUT from fp32 [C][17][17][17][17] to [17^4][4ch] float4 (16 B/entry).
__global__ __launch_bounds__(256) void pack_kernel(const float* __restrict__ src,
                                                   int n_ch,
                                                   float4* __restrict__ dst) {
    int e = blockIdx.x * 256 + threadIdx.x;
    if (e >= D4) return;
    float4 v;
    v.x = src[e];
    v.y = src[D4 + e];
    v.z = src[2 * D4 + e];
    v.w = (n_ch == 4) ? src[3 * D4 + e] : 0.f;
    dst[e] = v;
}

// Fused 6-stage quadrilinear chain, one thread per pixel.
// NUMERICS CONTRACT: bit-replicate the numpy float32 oracle.
//  - fp32 everywhere, NO FMA contraction (pragma above + per-function)
//  - weight product left-assoc ((w0*w1)*w2)*w3, corner order c=0..15 with
//    bit k of c selecting dim k (+1), accumulation strictly sequential in c
//  - clip(0,1) between stages, none after the last
__global__ __launch_bounds__(256) void fused_kernel(const float* __restrict__ vi,
                                                    const float* __restrict__ ir,
                                                    const float4* __restrict__ luts,
                                                    float* __restrict__ out) {
#pragma clang fp contract(off)
    int p = blockIdx.x * 256 + threadIdx.x;
    if (p >= NPIX) return;
    int b  = p >> 18;           // HW = 2^18
    int hw = p & (HW - 1);
    int vbase = (b * 3) << 18;

    float x0 = vi[vbase + hw];
    float x1 = vi[vbase + HW + hw];
    float x2 = vi[vbase + 2 * HW + hw];
    float x3 = ir[p];

    for (int s = 0; s < 6; ++s) {
        const float4* __restrict__ lut = luts + (size_t)s * D4;
        x0 = fminf(fmaxf(x0, 0.f), 1.f);
        x1 = fminf(fmaxf(x1, 0.f), 1.f);
        x2 = fminf(fmaxf(x2, 0.f), 1.f);
        x3 = fminf(fmaxf(x3, 0.f), 1.f);

        float xs0 = x0 * 16.f;
        float xs1 = x1 * 16.f;
        float xs2 = x2 * 16.f;
        float xs3 = x3 * 16.f;
        int i0 = (int)xs0; i0 = i0 > 15 ? 15 : i0;
        int i1 = (int)xs1; i1 = i1 > 15 ? 15 : i1;
        int i2 = (int)xs2; i2 = i2 > 15 ? 15 : i2;
        int i3 = (int)xs3; i3 = i3 > 15 ? 15 : i3;
        float f0 = xs0 - (float)i0;   // must stay mul-then-sub (no fma!)
        float f1 = xs1 - (float)i1;
        float f2 = xs2 - (float)i2;
        float f3 = xs3 - (float)i3;
        float g0 = 1.f - f0;
        float g1 = 1.f - f1;
        float g2 = 1.f - f2;
        float g3 = 1.f - f3;

        // w01[b1*2+b0] = (b0?f0:g0)*(b1?f1:g1) — the reference's first
        // left-assoc partial product for that corner.
        float w01[4] = { g0 * g1, f0 * g1, g0 * f1, f0 * f1 };

        int off = i0 * 4913 + i1 * 289 + i2 * 17 + i3;

        float a0 = 0.f, a1 = 0.f, a2 = 0.f, a3 = 0.f;
        // corner c_ref = hi*8 + c: bits (b0,b1,b2) = c, b3 = hi.
        // Strictly sequential accumulation in c_ref order 0..15.
#pragma unroll
        for (int hi = 0; hi < 2; ++hi) {
            float w3 = hi ? f3 : g3;
#pragma unroll
            for (int c = 0; c < 8; ++c) {
                int d = (c & 1) * 4913 + ((c >> 1) & 1) * 289 + (c >> 2) * 17 + hi;
                float4 v = lut[off + d];            // 16B-aligned dwordx4 gather
                float w012 = w01[c & 3] * ((c >> 2) ? f2 : g2);
                float w    = w012 * w3;
                if (hi == 0 && c == 0) {
                    a0 = v.x * w;
                    a1 = v.y * w;
                    a2 = v.z * w;
                    a3 = v.w * w;
                } else {
                    a0 = a0 + v.x * w;   // mul-then-add, contraction OFF
                    a1 = a1 + v.y * w;
                    a2 = a2 + v.z * w;
                    a3 = a3 + v.w * w;
                }
            }
        }
        x0 = a0; x1 = a1; x2 = a2; x3 = a3;
    }

    out[vbase + hw]          = x0;
    out[vbase + HW + hw]     = x1;
    out[vbase + 2 * HW + hw] = x2;
}

// Fallback (ws too small): same exact-order fp32, native [C][D^4] layout.
__global__ __launch_bounds__(256) void fused_fallback(const float* __restrict__ vi,
                                                      const float* __restrict__ ir,
                                                      const float* __restrict__ l8,
                                                      const float* __restrict__ l00,
                                                      const float* __restrict__ l01,
                                                      const float* __restrict__ l02,
                                                      const float* __restrict__ l03,
                                                      const float* __restrict__ lpgf,
                                                      float* __restrict__ out) {
#pragma clang fp contract(off)
    int p = blockIdx.x * 256 + threadIdx.x;
    if (p >= NPIX) return;
    int b  = p >> 18;
    int hw = p & (HW - 1);
    int vbase = (b * 3) << 18;

    const float* ptrs[6] = { l8, l00, l01, l02, l03, lpgf };

    float x0 = vi[vbase + hw];
    float x1 = vi[vbase + HW + hw];
    float x2 = vi[vbase + 2 * HW + hw];
    float x3 = ir[p];

    for (int s = 0; s < 6; ++s) {
        const float* __restrict__ L = ptrs[s];
        int n_ch = (s == 5) ? 3 : 4;
        x0 = fminf(fmaxf(x0, 0.f), 1.f);
        x1 = fminf(fmaxf(x1, 0.f), 1.f);
        x2 = fminf(fmaxf(x2, 0.f), 1.f);
        x3 = fminf(fmaxf(x3, 0.f), 1.f);
        float xs0 = x0 * 16.f;
        float xs1 = x1 * 16.f;
        float xs2 = x2 * 16.f;
        float xs3 = x3 * 16.f;
        int i0 = (int)xs0; i0 = i0 > 15 ? 15 : i0;
        int i1 = (int)xs1; i1 = i1 > 15 ? 15 : i1;
        int i2 = (int)xs2; i2 = i2 > 15 ? 15 : i2;
        int i3 = (int)xs3; i3 = i3 > 15 ? 15 : i3;
        float f0 = xs0 - (float)i0;
        float f1 = xs1 - (float)i1;
        float f2 = xs2 - (float)i2;
        float f3 = xs3 - (float)i3;
        float g0 = 1.f - f0;
        float g1 = 1.f - f1;
        float g2 = 1.f - f2;
        float g3 = 1.f - f3;
        float w01[4] = { g0 * g1, f0 * g1, g0 * f1, f0 * f1 };
        int off = i0 * 4913 + i1 * 289 + i2 * 17 + i3;
        float a0 = 0.f, a1 = 0.f, a2 = 0.f, a3 = 0.f;
        for (int cr = 0; cr < 16; ++cr) {
            int hi = cr >> 3, c = cr & 7;
            int idx = off + (c & 1) * 4913 + ((c >> 1) & 1) * 289 + (c >> 2) * 17 + hi;
            float w012 = w01[c & 3] * ((c >> 2) ? f2 : g2);
            float w    = w012 * (hi ? f3 : g3);
            float v0 = L[idx];
            float v1 = L[D4 + idx];
            float v2 = L[2 * D4 + idx];
            float v3 = (n_ch == 4) ? L[3 * D4 + idx] : 0.f;
            if (cr == 0) {
                a0 = v0 * w; a1 = v1 * w;
                a2 = v2 * w; a3 = v3 * w;
            } else {
                a0 = a0 + v0 * w;
                a1 = a1 + v1 * w;
                a2 = a2 + v2 * w;
                a3 = a3 + v3 * w;
            }
        }
        x0 = a0; x1 = a1; x2 = a2; x3 = a3;
    }

    out[vbase + hw]          = x0;
    out[vbase + HW + hw]     = x1;
    out[vbase + 2 * HW + hw] = x2;
}

extern "C" void kernel_launch(void* const* d_in, const int* in_sizes, int n_in,
                              void* d_out, int out_size, void* d_ws, size_t ws_size,
                              hipStream_t stream) {
    const float* vi = (const float*)d_in[0];
    const float* ir = (const float*)d_in[1];
    const float* raw[6] = {
        (const float*)d_in[2], (const float*)d_in[3],
        (const float*)d_in[4], (const float*)d_in[5],
        (const float*)d_in[6], (const float*)d_in[7]
    };
    float* out = (float*)d_out;

    size_t need = (size_t)6 * D4 * sizeof(float4);   // ~8.0 MB packed LUTs
    if (ws_size >= need) {
        float4* packed = (float4*)d_ws;
        int pack_blocks = (D4 + 255) / 256;
        for (int s = 0; s < 6; ++s) {
            pack_kernel<<<pack_blocks, 256, 0, stream>>>(raw[s], (s == 5) ? 3 : 4,
                                                         packed + (size_t)s * D4);
        }
        fused_kernel<<<NPIX / 256, 256, 0, stream>>>(vi, ir, packed, out);
    } else {
        fused_fallback<<<NPIX / 256, 256, 0, stream>>>(vi, ir, raw[0], raw[1], raw[2],
                                                       raw[3], raw[4], raw[5], out);
    }
}